// Round 1
// 1097.536 us; speedup vs baseline: 1.8978x; 1.8978x over previous
//
#include <hip/hip_runtime.h>

// Hartley spectral conv (fp32 I/O): B=16, Ci=Co=64, H=W=256, 64x64 modes (f=j-32).
// R3: kFwd/kInv rewritten on MFMA (v_mfma_f32_16x16x32_bf16).
// Numerics preserved vs the passing scalar version: every fp32 operand that the
// old kernel used in fp32 (X, trig) is split hi/lo bf16 (v = bf16(v) + bf16(v-bf16(v)))
// and multiplied with 3 MFMAs (xh*th + xl*th + xh*tl, missing term ~2^-18) or
// 2 MFMAs when the other operand was already bf16 (A/B, G, H). Same bf16 stage
// boundaries as before -> same absmax budget (~0.0078).
//
// MFMA frag layout (guide §3, m89/m92-verified):
//   a-frag: lane l -> row l&15,  k = (l>>4)*8 + e   (8 contiguous k, 16B)
//   b-frag: lane l -> col l&15,  k = (l>>4)*8 + e
//   d-frag: lane l, reg r -> row (l>>4)*4 + r, col l&15
// Trig is pre-packed by k0_pack in exactly this fragment order -> 16B coalesced
// L2-resident loads, no LDS for trig. Data tiles in LDS are stored transposed
// ([n][k], 16B-contiguous in k) with byte-XOR swizzle ^((row&7)<<4) (G4 recipe).

typedef unsigned short u16;
typedef unsigned int u32;
typedef __attribute__((ext_vector_type(8))) short short8;   // 8 bf16 = 4 VGPR
typedef __attribute__((ext_vector_type(4))) float f32x4;
typedef __attribute__((ext_vector_type(2))) u32 u32x2;

__device__ __forceinline__ float bf2f(u16 u) { union { u32 i; float f; } v; v.i = ((u32)u) << 16; return v.f; }
__device__ __forceinline__ u16 f2bf(float f) {
  u32 x = __float_as_uint(f);
  x += 0x7fffu + ((x >> 16) & 1u);   // round-to-nearest-even
  return (u16)(x >> 16);
}
__device__ __forceinline__ f32x4 mfma16(short8 a, short8 b, f32x4 c) {
  return __builtin_amdgcn_mfma_f32_16x16x32_bf16(a, b, c, 0, 0, 0);
}

// ---------------- k0_pack: fragment-packed hi/lo bf16 trig tables ----------------
// tb0 pb1 [kb8][nb8][l][e]:  fwd P1 B-op  T[x 256][j 128]   j<64: cos((j-32)x)  else sin((j-96)x)
// tb1 pa2 [mb8][kb16][l][e]: fwd P2 A-op  T[m 128][k 512]   m<64 (E): k<256 cos((fy)y) else -sin ; m>=64 (O): sin / cos
// tb2 pb3 [kb2][nb32][l][e]: inv PA B-op  T[jx 64][n 512]   n<256: cos((jx-32)x) else sin
// tb3 pa4 [mb16][kb4][l][e]: inv PB A-op  T[y 256][k 128]   k<64: cas+ = c+s  else cas- = c-s  (f=jy-32)
__global__ __launch_bounds__(256) void k0_pack(
    u16* __restrict__ pb1h, u16* __restrict__ pb1l,
    u16* __restrict__ pa2h, u16* __restrict__ pa2l,
    u16* __restrict__ pb3h, u16* __restrict__ pb3l,
    u16* __restrict__ pa4h, u16* __restrict__ pa4l) {
  const int idx = blockIdx.x * 256 + threadIdx.x;
  const int tb = blockIdx.y;
  const int e = idx & 7, l = (idx >> 3) & 63;
  const int lm = l & 15, lg = l >> 4;
  float v;
  u16 *ph, *pl;
  if (tb == 0) {
    if (idx >= 32768) return;
    int nb = (idx >> 9) & 7, kb = (idx >> 12) & 7;
    int k = kb * 32 + lg * 8 + e;            // x
    int n = nb * 16 + lm;                    // j in [0,128)
    int f = (n < 64) ? (n - 32) : (n - 96);
    int m = ((f * k) % 256 + 256) & 255;
    float s, c; sincosf((float)m * 0.0245436926061702596f, &s, &c);
    v = (n < 64) ? c : s;
    ph = pb1h; pl = pb1l;
  } else if (tb == 1) {
    int kb = (idx >> 9) & 15, mb = (idx >> 13) & 7;
    int mm = mb * 16 + lm;                   // row of [E;O]
    int k = kb * 32 + lg * 8 + e;            // (y, A|B half)
    int fy = (mm & 63) - 32;
    int y = k & 255;
    int m = ((fy * y) % 256 + 256) & 255;
    float s, c; sincosf((float)m * 0.0245436926061702596f, &s, &c);
    v = (mm < 64) ? ((k < 256) ? c : -s) : ((k < 256) ? s : c);
    ph = pa2h; pl = pa2l;
  } else if (tb == 2) {
    if (idx >= 32768) return;
    int nb = (idx >> 9) & 31, kb = (idx >> 14) & 1;
    int k = kb * 32 + lg * 8 + e;            // jx
    int n = nb * 16 + lm;                    // (x | 256+x)
    int f = k - 32;
    int xx = n & 255;
    int m = ((f * xx) % 256 + 256) & 255;
    float s, c; sincosf((float)m * 0.0245436926061702596f, &s, &c);
    v = (n < 256) ? c : s;
    ph = pb3h; pl = pb3l;
  } else {
    if (idx >= 32768) return;
    int kb = (idx >> 9) & 3, mb = (idx >> 11) & 15;
    int y = mb * 16 + lm;
    int k = kb * 32 + lg * 8 + e;            // (jy, P|M)
    int f = (k & 63) - 32;
    int m = ((f * y) % 256 + 256) & 255;
    float s, c; sincosf((float)m * 0.0245436926061702596f, &s, &c);
    v = (k < 64) ? (c + s) : (c - s);
    ph = pa4h; pl = pa4l;
  }
  u16 hb = f2bf(v);
  ph[idx] = hb;
  pl[idx] = f2bf(v - bf2f(hb));
}

// ---------------- kFwd: fused 2D forward partial DFT, one block per image ----------------
// P1: A|B[y 256][j 128] = Xsplit @ pb1 (3 mfma/prod) -> transposed swizzled LDS
// P2: [E;O][m 128][fx 64] = pa2[m][k 512] @ ABstack[k][fx] (2 mfma/prod)
__global__ __launch_bounds__(256, 2) void kFwd(const float* __restrict__ x,
    const u16* __restrict__ pb1h, const u16* __restrict__ pb1l,
    const u16* __restrict__ pa2h, const u16* __restrict__ pa2l,
    u16* __restrict__ E, u16* __restrict__ O) {
  __shared__ u16 ABT[32768];   // [j 128][y 256] bf16, byte ^ ((j&7)<<4), 64 KiB
  const int t = threadIdx.x;
  const int l = t & 63, w = t >> 6;
  const int lm = l & 15, lg = l >> 4;
  const int img = blockIdx.x;
  const float* xim = x + (long)img * 65536;

  // ---- phase 1: wave w owns y in [64w, 64w+64)
  f32x4 acc[4][8];
#pragma unroll
  for (int mt = 0; mt < 4; ++mt)
#pragma unroll
    for (int nb = 0; nb < 8; ++nb) acc[mt][nb] = (f32x4){0.f, 0.f, 0.f, 0.f};

  for (int kb = 0; kb < 8; ++kb) {
    short8 ah[4], al[4];
#pragma unroll
    for (int mt = 0; mt < 4; ++mt) {
      const float* px = xim + (long)(w * 64 + mt * 16 + lm) * 256 + kb * 32 + lg * 8;
      f32x4 v0 = *(const f32x4*)px;
      f32x4 v1 = *(const f32x4*)(px + 4);
#pragma unroll
      for (int i = 0; i < 8; ++i) {
        float vv = (i < 4) ? v0[i] : v1[i - 4];
        u16 hb = f2bf(vv);
        ah[mt][i] = (short)hb;
        al[mt][i] = (short)f2bf(vv - bf2f(hb));
      }
    }
#pragma unroll
    for (int nb = 0; nb < 8; ++nb) {
      long fo = (long)((kb * 8 + nb) * 64 + l) * 8;
      short8 bh = *(const short8*)(pb1h + fo);
      short8 bl = *(const short8*)(pb1l + fo);
#pragma unroll
      for (int mt = 0; mt < 4; ++mt) {
        acc[mt][nb] = mfma16(ah[mt], bh, acc[mt][nb]);
        acc[mt][nb] = mfma16(al[mt], bh, acc[mt][nb]);
        acc[mt][nb] = mfma16(ah[mt], bl, acc[mt][nb]);
      }
    }
  }
#pragma unroll
  for (int mt = 0; mt < 4; ++mt)
#pragma unroll
    for (int nb = 0; nb < 8; ++nb) {
      u32 j = (u32)(nb * 16 + lm);
      u32 y0 = (u32)(w * 64 + mt * 16 + lg * 4);
      u32 p0 = (u32)f2bf(acc[mt][nb][0]) | ((u32)f2bf(acc[mt][nb][1]) << 16);
      u32 p1 = (u32)f2bf(acc[mt][nb][2]) | ((u32)f2bf(acc[mt][nb][3]) << 16);
      u32 off = (j * 512 + y0 * 2) ^ ((j & 7) << 4);
      *(u32x2*)((char*)ABT + off) = (u32x2){p0, p1};
    }
  __syncthreads();

  // ---- phase 2: wave w owns rows m in [32w, 32w+32) of [E;O]
  f32x4 eo[2][4];
#pragma unroll
  for (int mt = 0; mt < 2; ++mt)
#pragma unroll
    for (int nb = 0; nb < 4; ++nb) eo[mt][nb] = (f32x4){0.f, 0.f, 0.f, 0.f};

  for (int kb = 0; kb < 16; ++kb) {
    short8 bfr[4];
    const int rbase = (kb < 8) ? 0 : 64;             // A-rows (cos cols) vs B-rows (sin cols)
    const u32 kbyte = (u32)(kb & 7) * 64 + (u32)lg * 16;
#pragma unroll
    for (int nb = 0; nb < 4; ++nb) {
      u32 row = (u32)(rbase + nb * 16 + lm);
      u32 off = (row * 512 + kbyte) ^ ((row & 7) << 4);
      bfr[nb] = *(const short8*)((const char*)ABT + off);
    }
#pragma unroll
    for (int mt = 0; mt < 2; ++mt) {
      int mb = w * 2 + mt;
      long fo = (long)((mb * 16 + kb) * 64 + l) * 8;
      short8 th = *(const short8*)(pa2h + fo);
      short8 tl = *(const short8*)(pa2l + fo);
#pragma unroll
      for (int nb = 0; nb < 4; ++nb) {
        eo[mt][nb] = mfma16(th, bfr[nb], eo[mt][nb]);
        eo[mt][nb] = mfma16(tl, bfr[nb], eo[mt][nb]);
      }
    }
  }
  u16* dst = (w < 2) ? E : O;
  const long ebase = (long)img * 4096;
  const int fyb = (w & 1) * 32;
#pragma unroll
  for (int mt = 0; mt < 2; ++mt)
#pragma unroll
    for (int nb = 0; nb < 4; ++nb) {
      int fy0 = fyb + mt * 16 + lg * 4;
      int fx = nb * 16 + lm;
#pragma unroll
      for (int r = 0; r < 4; ++r)
        dst[ebase + (long)(fy0 + r) * 64 + fx] = f2bf(eo[mt][nb][r]);
    }
}

// ---------------- u16 transpose: in[M][N] -> out[N][M] (z selects pair) ----------------
__global__ __launch_bounds__(256) void kt_u16(const u16* __restrict__ in0, u16* __restrict__ out0,
                                              const u16* __restrict__ in1, u16* __restrict__ out1,
                                              int M, int N) {
  __shared__ u16 tile[32][36];
  const u16* in = blockIdx.z ? in1 : in0;
  u16* out = blockIdx.z ? out1 : out0;
  int tx = threadIdx.x & 31, ty = threadIdx.x >> 5;
  long c0 = (long)blockIdx.x * 32, r0 = (long)blockIdx.y * 32;
#pragma unroll
  for (int i = 0; i < 4; ++i) {
    int r = ty + i * 8;
    tile[r][tx] = in[(r0 + r) * N + c0 + tx];
  }
  __syncthreads();
#pragma unroll
  for (int i = 0; i < 4; ++i) {
    int r = ty + i * 8;
    out[(c0 + r) * M + r0 + tx] = tile[tx][r];
  }
}

// ---------------- k5: per-mode channel mix, G[b][o] = sum_i E*w + O*kr (unchanged) ----------------
__global__ __launch_bounds__(256) void k5_mix(const u16* __restrict__ Et, const u16* __restrict__ Ot,
    const float* __restrict__ w, u16* __restrict__ Gt) {
  __shared__ float Ews[1024], Ows[1024];
  __shared__ float Ws[4096], Ks[4096];
  const int t = threadIdx.x;
  const int mode = blockIdx.x;
  const int jy = mode >> 6, jx = mode & 63;
  const int fm = (((64 - jy) & 63) << 6) | ((64 - jx) & 63);
  ushort4 ve = ((const ushort4*)Et)[(long)mode * 256 + t];
  ushort4 vo = ((const ushort4*)Ot)[(long)mode * 256 + t];
  Ews[t * 4 + 0] = bf2f(ve.x); Ews[t * 4 + 1] = bf2f(ve.y);
  Ews[t * 4 + 2] = bf2f(ve.z); Ews[t * 4 + 3] = bf2f(ve.w);
  Ows[t * 4 + 0] = bf2f(vo.x); Ows[t * 4 + 1] = bf2f(vo.y);
  Ows[t * 4 + 2] = bf2f(vo.z); Ows[t * 4 + 3] = bf2f(vo.w);
#pragma unroll
  for (int it = 0; it < 16; ++it) {
    int e = it * 256 + t;
    Ws[e] = w[(long)e * 4096 + mode];
    Ks[e] = w[(long)e * 4096 + fm];
  }
  __syncthreads();
  const int o = t & 63, bg = t >> 6;
  float acc[4] = {0.f, 0.f, 0.f, 0.f};
  for (int i = 0; i < 64; ++i) {
    float wv = Ws[i * 64 + o];
    float kv = Ks[i * 64 + o];
#pragma unroll
    for (int j = 0; j < 4; ++j) {
      int b = bg * 4 + j;
      acc[j] = fmaf(Ews[b * 64 + i], wv, acc[j]);
      acc[j] = fmaf(Ows[b * 64 + i], kv, acc[j]);
    }
  }
#pragma unroll
  for (int j = 0; j < 4; ++j)
    Gt[(long)mode * 1024 + (bg * 4 + j) * 64 + o] = f2bf(acc[j]);
}

// ---------------- kInv: fused 2D inverse, one block per output image (bo) ----------------
// PA: HH[k' 128][x] = G @ pb3 (2 mfma/prod) -> transposed swizzled LDS (half of x at a time)
// PB: out[y][x] = pa4[y][k 128] @ HHT, fused *(1/65536)+bias, relu
__global__ __launch_bounds__(256, 3) void kInv(const u16* __restrict__ G,
    const u16* __restrict__ pb3h, const u16* __restrict__ pb3l,
    const u16* __restrict__ pa4h, const u16* __restrict__ pa4l,
    const float* __restrict__ bias, float* __restrict__ out) {
  __shared__ u16 Gls[4096];     // [jy 64][jx 64], byte ^ ((jy&7)<<4), 8 KiB
  __shared__ u16 HHT[16384];    // [xl 128][k' 128], byte ^ ((xl&7)<<4), 32 KiB
  const int t = threadIdx.x;
  const int l = t & 63, w = t >> 6;
  const int lm = l & 15, lg = l >> 4;
  const int bo = blockIdx.x;

#pragma unroll
  for (int it = 0; it < 2; ++it) {
    int tt = t + it * 256;
    uint4 v = ((const uint4*)(G + (long)bo * 4096))[tt];
    u32 jy = (u32)(tt >> 3);
    u32 off = (jy * 128 + (u32)(tt & 7) * 16) ^ ((jy & 7) << 4);
    *(uint4*)((char*)Gls + off) = v;
  }
  __syncthreads();

  const float bv = bias[bo & 63];
  const int comp = w >> 1;        // 0: H1 (cos), 1: H2 (sin)
  const int xw = (w & 1) * 64;    // x offset inside the 128-wide half

  for (int h = 0; h < 2; ++h) {
    if (h) __syncthreads();       // phase-B reads of previous half done
    // ---- phase A: this wave computes comp-part, xl in [xw, xw+64)
    f32x4 ha[4][4];
#pragma unroll
    for (int mt = 0; mt < 4; ++mt)
#pragma unroll
      for (int nb = 0; nb < 4; ++nb) ha[mt][nb] = (f32x4){0.f, 0.f, 0.f, 0.f};

    const int nbase = comp * 16 + h * 8 + (w & 1) * 4;   // (comp*256 + h*128 + xw)/16
#pragma unroll
    for (int kb = 0; kb < 2; ++kb) {
      short8 af[4];
#pragma unroll
      for (int mt = 0; mt < 4; ++mt) {
        u32 row = (u32)(mt * 16 + lm);
        u32 off = (row * 128 + (u32)kb * 64 + (u32)lg * 16) ^ ((row & 7) << 4);
        af[mt] = *(const short8*)((const char*)Gls + off);
      }
#pragma unroll
      for (int nb = 0; nb < 4; ++nb) {
        long fo = (long)((kb * 32 + nbase + nb) * 64 + l) * 8;
        short8 bh = *(const short8*)(pb3h + fo);
        short8 bl = *(const short8*)(pb3l + fo);
#pragma unroll
        for (int mt = 0; mt < 4; ++mt) {
          ha[mt][nb] = mfma16(af[mt], bh, ha[mt][nb]);
          ha[mt][nb] = mfma16(af[mt], bl, ha[mt][nb]);
        }
      }
    }
#pragma unroll
    for (int mt = 0; mt < 4; ++mt)
#pragma unroll
      for (int nb = 0; nb < 4; ++nb) {
        u32 xl = (u32)(xw + nb * 16 + lm);
        u32 kp = (u32)(comp * 64 + mt * 16 + lg * 4);
        u32 p0 = (u32)f2bf(ha[mt][nb][0]) | ((u32)f2bf(ha[mt][nb][1]) << 16);
        u32 p1 = (u32)f2bf(ha[mt][nb][2]) | ((u32)f2bf(ha[mt][nb][3]) << 16);
        u32 off = (xl * 256 + kp * 2) ^ ((xl & 7) << 4);
        *(u32x2*)((char*)HHT + off) = (u32x2){p0, p1};
      }
    __syncthreads();

    // ---- phase B: wave w owns y in [64w, 64w+64); x = this half
#pragma unroll
    for (int q = 0; q < 2; ++q) {
      f32x4 oa[4][4];
#pragma unroll
      for (int mt = 0; mt < 4; ++mt)
#pragma unroll
        for (int nb = 0; nb < 4; ++nb) oa[mt][nb] = (f32x4){0.f, 0.f, 0.f, 0.f};
#pragma unroll
      for (int kb = 0; kb < 4; ++kb) {
        short8 bf_[4];
#pragma unroll
        for (int nb = 0; nb < 4; ++nb) {
          u32 xl = (u32)(q * 64 + nb * 16 + lm);
          u32 off = (xl * 256 + (u32)kb * 64 + (u32)lg * 16) ^ ((xl & 7) << 4);
          bf_[nb] = *(const short8*)((const char*)HHT + off);
        }
#pragma unroll
        for (int mt = 0; mt < 4; ++mt) {
          int mb = w * 4 + mt;
          long fo = (long)((mb * 4 + kb) * 64 + l) * 8;
          short8 th = *(const short8*)(pa4h + fo);
          short8 tl = *(const short8*)(pa4l + fo);
#pragma unroll
          for (int nb = 0; nb < 4; ++nb) {
            oa[mt][nb] = mfma16(th, bf_[nb], oa[mt][nb]);
            oa[mt][nb] = mfma16(tl, bf_[nb], oa[mt][nb]);
          }
        }
      }
      const float inv = 1.0f / 65536.0f;
#pragma unroll
      for (int mt = 0; mt < 4; ++mt)
#pragma unroll
        for (int nb = 0; nb < 4; ++nb) {
          int y0 = w * 64 + mt * 16 + lg * 4;
          int xx = h * 128 + q * 64 + nb * 16 + lm;
#pragma unroll
          for (int r = 0; r < 4; ++r) {
            float v = fmaf(oa[mt][nb][r], inv, bv);
            out[(long)bo * 65536 + (long)(y0 + r) * 256 + xx] = fmaxf(v, 0.f);
          }
        }
    }
  }
}

extern "C" void kernel_launch(void* const* d_in, const int* in_sizes, int n_in,
                              void* d_out, int out_size, void* d_ws, size_t ws_size,
                              hipStream_t stream) {
  const float* x    = (const float*)d_in[0];   // [16][64][256][256] fp32
  const float* w    = (const float*)d_in[1];   // [64][64][64][64]   fp32
  const float* bias = (const float*)d_in[2];   // [64]               fp32
  float* out = (float*)d_out;                  // [16][64][256][256] fp32
  char* ws = (char*)d_ws;

  // persistent tables (needed by kInv at the end):
  u16* pb3h = (u16*)(ws + 0);
  u16* pb3l = (u16*)(ws + 65536);
  u16* pa4h = (u16*)(ws + 131072);
  u16* pa4l = (u16*)(ws + 196608);
  // E/O [img][mode] bf16, 8 MiB each:
  u16* E    = (u16*)(ws + 262144);
  u16* O    = (u16*)(ws + 8650752);
  u16* Et   = (u16*)(ws + 17039360);
  u16* Ot   = (u16*)(ws + 25427968);
  // transient fwd tables live in the head of the (not-yet-written) Et region;
  // kt_u16 #1 clobbers them only after kFwd has finished reading them:
  u16* pb1h = (u16*)(ws + 17039360);
  u16* pb1l = (u16*)(ws + 17104896);
  u16* pa2h = (u16*)(ws + 17170432);
  u16* pa2l = (u16*)(ws + 17301504);
  u16* Gt   = (u16*)(ws + 262144);     // over dead E
  u16* G    = (u16*)(ws + 8650752);    // over dead O
  // peak workspace: 33,816,576 bytes (< previous 33,947,648)

  k0_pack<<<dim3(256, 4), 256, 0, stream>>>(pb1h, pb1l, pa2h, pa2l, pb3h, pb3l, pa4h, pa4l);
  kFwd   <<<1024, 256, 0, stream>>>(x, pb1h, pb1l, pa2h, pa2l, E, O);
  kt_u16 <<<dim3(128, 32, 2), 256, 0, stream>>>(E, Et, O, Ot, 1024, 4096);
  k5_mix <<<4096, 256, 0, stream>>>(Et, Ot, w, Gt);
  kt_u16 <<<dim3(32, 128, 1), 256, 0, stream>>>(Gt, G, Gt, G, 4096, 1024);
  kInv   <<<1024, 256, 0, stream>>>(G, pb3h, pb3l, pa4h, pa4l, bias, out);
}

// Round 2
// 837.538 us; speedup vs baseline: 2.4869x; 1.3104x over previous
//
#include <hip/hip_runtime.h>

// Hartley spectral conv (fp32 I/O): B=16, Ci=Co=64, H=W=256, 64x64 modes (f=j-32).
// R4: k5_mix was the top dispatch (320us, FETCH 1.1GB vs 128MB useful -> 8x
// over-fetch from 16KB-strided w[e*4096+mode] gathers). Fix: one-time tiled
// transpose of w into mode-major w2[mode][e] (fp32, numerics identical), staged
// in the HEAD OF d_out (256MB, only written by kInv at the very end -> free
// 64MB scratch, zero workspace growth). k5_mix now reads two contiguous 16KB
// rows (mode, flipped mode) via float4.
// kFwd/kInv: MFMA (v_mfma_f32_16x16x32_bf16) with hi/lo bf16 splits -- unchanged.

typedef unsigned short u16;
typedef unsigned int u32;
typedef __attribute__((ext_vector_type(8))) short short8;   // 8 bf16 = 4 VGPR
typedef __attribute__((ext_vector_type(4))) float f32x4;
typedef __attribute__((ext_vector_type(2))) u32 u32x2;

__device__ __forceinline__ float bf2f(u16 u) { union { u32 i; float f; } v; v.i = ((u32)u) << 16; return v.f; }
__device__ __forceinline__ u16 f2bf(float f) {
  u32 x = __float_as_uint(f);
  x += 0x7fffu + ((x >> 16) & 1u);   // round-to-nearest-even
  return (u16)(x >> 16);
}
__device__ __forceinline__ f32x4 mfma16(short8 a, short8 b, f32x4 c) {
  return __builtin_amdgcn_mfma_f32_16x16x32_bf16(a, b, c, 0, 0, 0);
}

// ---------------- k0_pack: fragment-packed hi/lo bf16 trig tables ----------------
// tb0 pb1 [kb8][nb8][l][e]:  fwd P1 B-op  T[x 256][j 128]   j<64: cos((j-32)x)  else sin((j-96)x)
// tb1 pa2 [mb8][kb16][l][e]: fwd P2 A-op  T[m 128][k 512]   m<64 (E): k<256 cos((fy)y) else -sin ; m>=64 (O): sin / cos
// tb2 pb3 [kb2][nb32][l][e]: inv PA B-op  T[jx 64][n 512]   n<256: cos((jx-32)x) else sin
// tb3 pa4 [mb16][kb4][l][e]: inv PB A-op  T[y 256][k 128]   k<64: cas+ = c+s  else cas- = c-s  (f=jy-32)
__global__ __launch_bounds__(256) void k0_pack(
    u16* __restrict__ pb1h, u16* __restrict__ pb1l,
    u16* __restrict__ pa2h, u16* __restrict__ pa2l,
    u16* __restrict__ pb3h, u16* __restrict__ pb3l,
    u16* __restrict__ pa4h, u16* __restrict__ pa4l) {
  const int idx = blockIdx.x * 256 + threadIdx.x;
  const int tb = blockIdx.y;
  const int e = idx & 7, l = (idx >> 3) & 63;
  const int lm = l & 15, lg = l >> 4;
  float v;
  u16 *ph, *pl;
  if (tb == 0) {
    if (idx >= 32768) return;
    int nb = (idx >> 9) & 7, kb = (idx >> 12) & 7;
    int k = kb * 32 + lg * 8 + e;            // x
    int n = nb * 16 + lm;                    // j in [0,128)
    int f = (n < 64) ? (n - 32) : (n - 96);
    int m = ((f * k) % 256 + 256) & 255;
    float s, c; sincosf((float)m * 0.0245436926061702596f, &s, &c);
    v = (n < 64) ? c : s;
    ph = pb1h; pl = pb1l;
  } else if (tb == 1) {
    int kb = (idx >> 9) & 15, mb = (idx >> 13) & 7;
    int mm = mb * 16 + lm;                   // row of [E;O]
    int k = kb * 32 + lg * 8 + e;            // (y, A|B half)
    int fy = (mm & 63) - 32;
    int y = k & 255;
    int m = ((fy * y) % 256 + 256) & 255;
    float s, c; sincosf((float)m * 0.0245436926061702596f, &s, &c);
    v = (mm < 64) ? ((k < 256) ? c : -s) : ((k < 256) ? s : c);
    ph = pa2h; pl = pa2l;
  } else if (tb == 2) {
    if (idx >= 32768) return;
    int nb = (idx >> 9) & 31, kb = (idx >> 14) & 1;
    int k = kb * 32 + lg * 8 + e;            // jx
    int n = nb * 16 + lm;                    // (x | 256+x)
    int f = k - 32;
    int xx = n & 255;
    int m = ((f * xx) % 256 + 256) & 255;
    float s, c; sincosf((float)m * 0.0245436926061702596f, &s, &c);
    v = (n < 256) ? c : s;
    ph = pb3h; pl = pb3l;
  } else {
    if (idx >= 32768) return;
    int kb = (idx >> 9) & 3, mb = (idx >> 11) & 15;
    int y = mb * 16 + lm;
    int k = kb * 32 + lg * 8 + e;            // (jy, P|M)
    int f = (k & 63) - 32;
    int m = ((f * y) % 256 + 256) & 255;
    float s, c; sincosf((float)m * 0.0245436926061702596f, &s, &c);
    v = (k < 64) ? (c + s) : (c - s);
    ph = pa4h; pl = pa4l;
  }
  u16 hb = f2bf(v);
  ph[idx] = hb;
  pl[idx] = f2bf(v - bf2f(hb));
}

// ---------------- kFwd: fused 2D forward partial DFT, one block per image ----------------
// P1: A|B[y 256][j 128] = Xsplit @ pb1 (3 mfma/prod) -> transposed swizzled LDS
// P2: [E;O][m 128][fx 64] = pa2[m][k 512] @ ABstack[k][fx] (2 mfma/prod)
__global__ __launch_bounds__(256, 2) void kFwd(const float* __restrict__ x,
    const u16* __restrict__ pb1h, const u16* __restrict__ pb1l,
    const u16* __restrict__ pa2h, const u16* __restrict__ pa2l,
    u16* __restrict__ E, u16* __restrict__ O) {
  __shared__ u16 ABT[32768];   // [j 128][y 256] bf16, byte ^ ((j&7)<<4), 64 KiB
  const int t = threadIdx.x;
  const int l = t & 63, w = t >> 6;
  const int lm = l & 15, lg = l >> 4;
  const int img = blockIdx.x;
  const float* xim = x + (long)img * 65536;

  // ---- phase 1: wave w owns y in [64w, 64w+64)
  f32x4 acc[4][8];
#pragma unroll
  for (int mt = 0; mt < 4; ++mt)
#pragma unroll
    for (int nb = 0; nb < 8; ++nb) acc[mt][nb] = (f32x4){0.f, 0.f, 0.f, 0.f};

  for (int kb = 0; kb < 8; ++kb) {
    short8 ah[4], al[4];
#pragma unroll
    for (int mt = 0; mt < 4; ++mt) {
      const float* px = xim + (long)(w * 64 + mt * 16 + lm) * 256 + kb * 32 + lg * 8;
      f32x4 v0 = *(const f32x4*)px;
      f32x4 v1 = *(const f32x4*)(px + 4);
#pragma unroll
      for (int i = 0; i < 8; ++i) {
        float vv = (i < 4) ? v0[i] : v1[i - 4];
        u16 hb = f2bf(vv);
        ah[mt][i] = (short)hb;
        al[mt][i] = (short)f2bf(vv - bf2f(hb));
      }
    }
#pragma unroll
    for (int nb = 0; nb < 8; ++nb) {
      long fo = (long)((kb * 8 + nb) * 64 + l) * 8;
      short8 bh = *(const short8*)(pb1h + fo);
      short8 bl = *(const short8*)(pb1l + fo);
#pragma unroll
      for (int mt = 0; mt < 4; ++mt) {
        acc[mt][nb] = mfma16(ah[mt], bh, acc[mt][nb]);
        acc[mt][nb] = mfma16(al[mt], bh, acc[mt][nb]);
        acc[mt][nb] = mfma16(ah[mt], bl, acc[mt][nb]);
      }
    }
  }
#pragma unroll
  for (int mt = 0; mt < 4; ++mt)
#pragma unroll
    for (int nb = 0; nb < 8; ++nb) {
      u32 j = (u32)(nb * 16 + lm);
      u32 y0 = (u32)(w * 64 + mt * 16 + lg * 4);
      u32 p0 = (u32)f2bf(acc[mt][nb][0]) | ((u32)f2bf(acc[mt][nb][1]) << 16);
      u32 p1 = (u32)f2bf(acc[mt][nb][2]) | ((u32)f2bf(acc[mt][nb][3]) << 16);
      u32 off = (j * 512 + y0 * 2) ^ ((j & 7) << 4);
      *(u32x2*)((char*)ABT + off) = (u32x2){p0, p1};
    }
  __syncthreads();

  // ---- phase 2: wave w owns rows m in [32w, 32w+32) of [E;O]
  f32x4 eo[2][4];
#pragma unroll
  for (int mt = 0; mt < 2; ++mt)
#pragma unroll
    for (int nb = 0; nb < 4; ++nb) eo[mt][nb] = (f32x4){0.f, 0.f, 0.f, 0.f};

  for (int kb = 0; kb < 16; ++kb) {
    short8 bfr[4];
    const int rbase = (kb < 8) ? 0 : 64;             // A-rows (cos cols) vs B-rows (sin cols)
    const u32 kbyte = (u32)(kb & 7) * 64 + (u32)lg * 16;
#pragma unroll
    for (int nb = 0; nb < 4; ++nb) {
      u32 row = (u32)(rbase + nb * 16 + lm);
      u32 off = (row * 512 + kbyte) ^ ((row & 7) << 4);
      bfr[nb] = *(const short8*)((const char*)ABT + off);
    }
#pragma unroll
    for (int mt = 0; mt < 2; ++mt) {
      int mb = w * 2 + mt;
      long fo = (long)((mb * 16 + kb) * 64 + l) * 8;
      short8 th = *(const short8*)(pa2h + fo);
      short8 tl = *(const short8*)(pa2l + fo);
#pragma unroll
      for (int nb = 0; nb < 4; ++nb) {
        eo[mt][nb] = mfma16(th, bfr[nb], eo[mt][nb]);
        eo[mt][nb] = mfma16(tl, bfr[nb], eo[mt][nb]);
      }
    }
  }
  u16* dst = (w < 2) ? E : O;
  const long ebase = (long)img * 4096;
  const int fyb = (w & 1) * 32;
#pragma unroll
  for (int mt = 0; mt < 2; ++mt)
#pragma unroll
    for (int nb = 0; nb < 4; ++nb) {
      int fy0 = fyb + mt * 16 + lg * 4;
      int fx = nb * 16 + lm;
#pragma unroll
      for (int r = 0; r < 4; ++r)
        dst[ebase + (long)(fy0 + r) * 64 + fx] = f2bf(eo[mt][nb][r]);
    }
}

// ---------------- u16 transpose: in[M][N] -> out[N][M] (z selects pair) ----------------
__global__ __launch_bounds__(256) void kt_u16(const u16* __restrict__ in0, u16* __restrict__ out0,
                                              const u16* __restrict__ in1, u16* __restrict__ out1,
                                              int M, int N) {
  __shared__ u16 tile[32][36];
  const u16* in = blockIdx.z ? in1 : in0;
  u16* out = blockIdx.z ? out1 : out0;
  int tx = threadIdx.x & 31, ty = threadIdx.x >> 5;
  long c0 = (long)blockIdx.x * 32, r0 = (long)blockIdx.y * 32;
#pragma unroll
  for (int i = 0; i < 4; ++i) {
    int r = ty + i * 8;
    tile[r][tx] = in[(r0 + r) * N + c0 + tx];
  }
  __syncthreads();
#pragma unroll
  for (int i = 0; i < 4; ++i) {
    int r = ty + i * 8;
    out[(c0 + r) * M + r0 + tx] = tile[tx][r];
  }
}

// ---------------- kt_f32: fp32 transpose w[e 4096][mode 4096] -> w2[mode][e] ----------------
__global__ __launch_bounds__(256) void kt_f32(const float* __restrict__ in, float* __restrict__ out) {
  __shared__ float tile[32][33];
  int tx = threadIdx.x & 31, ty = threadIdx.x >> 5;
  long c0 = (long)blockIdx.x * 32, r0 = (long)blockIdx.y * 32;
#pragma unroll
  for (int i = 0; i < 4; ++i) {
    int r = ty + i * 8;
    tile[r][tx] = in[(r0 + r) * 4096 + c0 + tx];
  }
  __syncthreads();
#pragma unroll
  for (int i = 0; i < 4; ++i) {
    int r = ty + i * 8;
    out[(c0 + r) * 4096 + r0 + tx] = tile[tx][r];
  }
}

// ---------------- k5: per-mode channel mix, G[b][o] = sum_i E*w + O*kr ----------------
// R4: reads mode-major w2[mode][e] -- two contiguous 16KB rows per block, float4.
__global__ __launch_bounds__(256) void k5_mix(const u16* __restrict__ Et, const u16* __restrict__ Ot,
    const float* __restrict__ w2, u16* __restrict__ Gt) {
  __shared__ float Ews[1024], Ows[1024];
  __shared__ float Ws[4096], Ks[4096];
  const int t = threadIdx.x;
  const int mode = blockIdx.x;
  const int jy = mode >> 6, jx = mode & 63;
  const int fm = (((64 - jy) & 63) << 6) | ((64 - jx) & 63);
  ushort4 ve = ((const ushort4*)Et)[(long)mode * 256 + t];
  ushort4 vo = ((const ushort4*)Ot)[(long)mode * 256 + t];
  Ews[t * 4 + 0] = bf2f(ve.x); Ews[t * 4 + 1] = bf2f(ve.y);
  Ews[t * 4 + 2] = bf2f(ve.z); Ews[t * 4 + 3] = bf2f(ve.w);
  Ows[t * 4 + 0] = bf2f(vo.x); Ows[t * 4 + 1] = bf2f(vo.y);
  Ows[t * 4 + 2] = bf2f(vo.z); Ows[t * 4 + 3] = bf2f(vo.w);
  const float4* wr = (const float4*)(w2 + (long)mode * 4096);
  const float4* kr = (const float4*)(w2 + (long)fm * 4096);
#pragma unroll
  for (int it = 0; it < 4; ++it) {
    ((float4*)Ws)[it * 256 + t] = wr[it * 256 + t];
    ((float4*)Ks)[it * 256 + t] = kr[it * 256 + t];
  }
  __syncthreads();
  const int o = t & 63, bg = t >> 6;
  float acc[4] = {0.f, 0.f, 0.f, 0.f};
  for (int i = 0; i < 64; ++i) {
    float wv = Ws[i * 64 + o];
    float kv = Ks[i * 64 + o];
#pragma unroll
    for (int j = 0; j < 4; ++j) {
      int b = bg * 4 + j;
      acc[j] = fmaf(Ews[b * 64 + i], wv, acc[j]);
      acc[j] = fmaf(Ows[b * 64 + i], kv, acc[j]);
    }
  }
#pragma unroll
  for (int j = 0; j < 4; ++j)
    Gt[(long)mode * 1024 + (bg * 4 + j) * 64 + o] = f2bf(acc[j]);
}

// ---------------- kInv: fused 2D inverse, one block per output image (bo) ----------------
// PA: HH[k' 128][x] = G @ pb3 (2 mfma/prod) -> transposed swizzled LDS (half of x at a time)
// PB: out[y][x] = pa4[y][k 128] @ HHT, fused *(1/65536)+bias, relu
__global__ __launch_bounds__(256, 3) void kInv(const u16* __restrict__ G,
    const u16* __restrict__ pb3h, const u16* __restrict__ pb3l,
    const u16* __restrict__ pa4h, const u16* __restrict__ pa4l,
    const float* __restrict__ bias, float* __restrict__ out) {
  __shared__ u16 Gls[4096];     // [jy 64][jx 64], byte ^ ((jy&7)<<4), 8 KiB
  __shared__ u16 HHT[16384];    // [xl 128][k' 128], byte ^ ((xl&7)<<4), 32 KiB
  const int t = threadIdx.x;
  const int l = t & 63, w = t >> 6;
  const int lm = l & 15, lg = l >> 4;
  const int bo = blockIdx.x;

#pragma unroll
  for (int it = 0; it < 2; ++it) {
    int tt = t + it * 256;
    uint4 v = ((const uint4*)(G + (long)bo * 4096))[tt];
    u32 jy = (u32)(tt >> 3);
    u32 off = (jy * 128 + (u32)(tt & 7) * 16) ^ ((jy & 7) << 4);
    *(uint4*)((char*)Gls + off) = v;
  }
  __syncthreads();

  const float bv = bias[bo & 63];
  const int comp = w >> 1;        // 0: H1 (cos), 1: H2 (sin)
  const int xw = (w & 1) * 64;    // x offset inside the 128-wide half

  for (int h = 0; h < 2; ++h) {
    if (h) __syncthreads();       // phase-B reads of previous half done
    // ---- phase A: this wave computes comp-part, xl in [xw, xw+64)
    f32x4 ha[4][4];
#pragma unroll
    for (int mt = 0; mt < 4; ++mt)
#pragma unroll
      for (int nb = 0; nb < 4; ++nb) ha[mt][nb] = (f32x4){0.f, 0.f, 0.f, 0.f};

    const int nbase = comp * 16 + h * 8 + (w & 1) * 4;   // (comp*256 + h*128 + xw)/16
#pragma unroll
    for (int kb = 0; kb < 2; ++kb) {
      short8 af[4];
#pragma unroll
      for (int mt = 0; mt < 4; ++mt) {
        u32 row = (u32)(mt * 16 + lm);
        u32 off = (row * 128 + (u32)kb * 64 + (u32)lg * 16) ^ ((row & 7) << 4);
        af[mt] = *(const short8*)((const char*)Gls + off);
      }
#pragma unroll
      for (int nb = 0; nb < 4; ++nb) {
        long fo = (long)((kb * 32 + nbase + nb) * 64 + l) * 8;
        short8 bh = *(const short8*)(pb3h + fo);
        short8 bl = *(const short8*)(pb3l + fo);
#pragma unroll
        for (int mt = 0; mt < 4; ++mt) {
          ha[mt][nb] = mfma16(af[mt], bh, ha[mt][nb]);
          ha[mt][nb] = mfma16(af[mt], bl, ha[mt][nb]);
        }
      }
    }
#pragma unroll
    for (int mt = 0; mt < 4; ++mt)
#pragma unroll
      for (int nb = 0; nb < 4; ++nb) {
        u32 xl = (u32)(xw + nb * 16 + lm);
        u32 kp = (u32)(comp * 64 + mt * 16 + lg * 4);
        u32 p0 = (u32)f2bf(ha[mt][nb][0]) | ((u32)f2bf(ha[mt][nb][1]) << 16);
        u32 p1 = (u32)f2bf(ha[mt][nb][2]) | ((u32)f2bf(ha[mt][nb][3]) << 16);
        u32 off = (xl * 256 + kp * 2) ^ ((xl & 7) << 4);
        *(u32x2*)((char*)HHT + off) = (u32x2){p0, p1};
      }
    __syncthreads();

    // ---- phase B: wave w owns y in [64w, 64w+64); x = this half
#pragma unroll
    for (int q = 0; q < 2; ++q) {
      f32x4 oa[4][4];
#pragma unroll
      for (int mt = 0; mt < 4; ++mt)
#pragma unroll
        for (int nb = 0; nb < 4; ++nb) oa[mt][nb] = (f32x4){0.f, 0.f, 0.f, 0.f};
#pragma unroll
      for (int kb = 0; kb < 4; ++kb) {
        short8 bf_[4];
#pragma unroll
        for (int nb = 0; nb < 4; ++nb) {
          u32 xl = (u32)(q * 64 + nb * 16 + lm);
          u32 off = (xl * 256 + (u32)kb * 64 + (u32)lg * 16) ^ ((xl & 7) << 4);
          bf_[nb] = *(const short8*)((const char*)HHT + off);
        }
#pragma unroll
        for (int mt = 0; mt < 4; ++mt) {
          int mb = w * 4 + mt;
          long fo = (long)((mb * 4 + kb) * 64 + l) * 8;
          short8 th = *(const short8*)(pa4h + fo);
          short8 tl = *(const short8*)(pa4l + fo);
#pragma unroll
          for (int nb = 0; nb < 4; ++nb) {
            oa[mt][nb] = mfma16(th, bf_[nb], oa[mt][nb]);
            oa[mt][nb] = mfma16(tl, bf_[nb], oa[mt][nb]);
          }
        }
      }
      const float inv = 1.0f / 65536.0f;
#pragma unroll
      for (int mt = 0; mt < 4; ++mt)
#pragma unroll
        for (int nb = 0; nb < 4; ++nb) {
          int y0 = w * 64 + mt * 16 + lg * 4;
          int xx = h * 128 + q * 64 + nb * 16 + lm;
#pragma unroll
          for (int r = 0; r < 4; ++r) {
            float v = fmaf(oa[mt][nb][r], inv, bv);
            out[(long)bo * 65536 + (long)(y0 + r) * 256 + xx] = fmaxf(v, 0.f);
          }
        }
    }
  }
}

extern "C" void kernel_launch(void* const* d_in, const int* in_sizes, int n_in,
                              void* d_out, int out_size, void* d_ws, size_t ws_size,
                              hipStream_t stream) {
  const float* x    = (const float*)d_in[0];   // [16][64][256][256] fp32
  const float* w    = (const float*)d_in[1];   // [64][64][64][64]   fp32
  const float* bias = (const float*)d_in[2];   // [64]               fp32
  float* out = (float*)d_out;                  // [16][64][256][256] fp32
  char* ws = (char*)d_ws;

  // persistent tables (needed by kInv at the end):
  u16* pb3h = (u16*)(ws + 0);
  u16* pb3l = (u16*)(ws + 65536);
  u16* pa4h = (u16*)(ws + 131072);
  u16* pa4l = (u16*)(ws + 196608);
  // E/O [img][mode] bf16, 8 MiB each:
  u16* E    = (u16*)(ws + 262144);
  u16* O    = (u16*)(ws + 8650752);
  u16* Et   = (u16*)(ws + 17039360);
  u16* Ot   = (u16*)(ws + 25427968);
  // transient fwd tables live in the head of the (not-yet-written) Et region;
  // kt_u16 #1 clobbers them only after kFwd has finished reading them:
  u16* pb1h = (u16*)(ws + 17039360);
  u16* pb1l = (u16*)(ws + 17104896);
  u16* pa2h = (u16*)(ws + 17170432);
  u16* pa2l = (u16*)(ws + 17301504);
  u16* Gt   = (u16*)(ws + 262144);     // over dead E
  u16* G    = (u16*)(ws + 8650752);    // over dead O
  // peak workspace: 33,816,576 bytes (unchanged)

  // w2[mode][e] fp32 (64 MB) lives in the HEAD OF d_out -- d_out is 256 MB and
  // is only written by kInv (last kernel), so the scratch lifetime is safe.
  float* w2 = (float*)d_out;

  k0_pack<<<dim3(256, 4), 256, 0, stream>>>(pb1h, pb1l, pa2h, pa2l, pb3h, pb3l, pa4h, pa4l);
  kt_f32 <<<dim3(128, 128), 256, 0, stream>>>(w, w2);
  kFwd   <<<1024, 256, 0, stream>>>(x, pb1h, pb1l, pa2h, pa2l, E, O);
  kt_u16 <<<dim3(128, 32, 2), 256, 0, stream>>>(E, Et, O, Ot, 1024, 4096);
  k5_mix <<<4096, 256, 0, stream>>>(Et, Ot, w2, Gt);
  kt_u16 <<<dim3(32, 128, 1), 256, 0, stream>>>(Gt, G, Gt, G, 4096, 1024);
  kInv   <<<1024, 256, 0, stream>>>(G, pb3h, pb3l, pa4h, pa4l, bias, out);
}

// Round 3
// 691.368 us; speedup vs baseline: 3.0127x; 1.2114x over previous
//
#include <hip/hip_runtime.h>

// Hartley spectral conv (fp32 I/O): B=16, Ci=Co=64, H=W=256, 64x64 modes (f=j-32).
// R5: kInv was top dispatch (306us) with FETCH=307MB (~= whole out array: store
// write-allocate/RFO) and WRITE=536MB (2x out: half-line-granular scalar stores).
// Fix: epilogue bounces each wave's 16x64 f32 out-subtile through a private LDS
// staging tile (pad 68, wave-local, no barrier), re-reads as float4/lane, and
// stores 256B-contiguous full 128B lines per 16-lane group with
// __builtin_nontemporal_store (no L2 allocate -> no RFO). Values & order identical.
// R4: k5_mix reads mode-major w2 (transposed into d_out head). kFwd/kInv on MFMA.

typedef unsigned short u16;
typedef unsigned int u32;
typedef __attribute__((ext_vector_type(8))) short short8;   // 8 bf16 = 4 VGPR
typedef __attribute__((ext_vector_type(4))) float f32x4;
typedef __attribute__((ext_vector_type(2))) u32 u32x2;

__device__ __forceinline__ float bf2f(u16 u) { union { u32 i; float f; } v; v.i = ((u32)u) << 16; return v.f; }
__device__ __forceinline__ u16 f2bf(float f) {
  u32 x = __float_as_uint(f);
  x += 0x7fffu + ((x >> 16) & 1u);   // round-to-nearest-even
  return (u16)(x >> 16);
}
__device__ __forceinline__ f32x4 mfma16(short8 a, short8 b, f32x4 c) {
  return __builtin_amdgcn_mfma_f32_16x16x32_bf16(a, b, c, 0, 0, 0);
}

// ---------------- k0_pack: fragment-packed hi/lo bf16 trig tables ----------------
// tb0 pb1 [kb8][nb8][l][e]:  fwd P1 B-op  T[x 256][j 128]   j<64: cos((j-32)x)  else sin((j-96)x)
// tb1 pa2 [mb8][kb16][l][e]: fwd P2 A-op  T[m 128][k 512]   m<64 (E): k<256 cos((fy)y) else -sin ; m>=64 (O): sin / cos
// tb2 pb3 [kb2][nb32][l][e]: inv PA B-op  T[jx 64][n 512]   n<256: cos((jx-32)x) else sin
// tb3 pa4 [mb16][kb4][l][e]: inv PB A-op  T[y 256][k 128]   k<64: cas+ = c+s  else cas- = c-s  (f=jy-32)
__global__ __launch_bounds__(256) void k0_pack(
    u16* __restrict__ pb1h, u16* __restrict__ pb1l,
    u16* __restrict__ pa2h, u16* __restrict__ pa2l,
    u16* __restrict__ pb3h, u16* __restrict__ pb3l,
    u16* __restrict__ pa4h, u16* __restrict__ pa4l) {
  const int idx = blockIdx.x * 256 + threadIdx.x;
  const int tb = blockIdx.y;
  const int e = idx & 7, l = (idx >> 3) & 63;
  const int lm = l & 15, lg = l >> 4;
  float v;
  u16 *ph, *pl;
  if (tb == 0) {
    if (idx >= 32768) return;
    int nb = (idx >> 9) & 7, kb = (idx >> 12) & 7;
    int k = kb * 32 + lg * 8 + e;            // x
    int n = nb * 16 + lm;                    // j in [0,128)
    int f = (n < 64) ? (n - 32) : (n - 96);
    int m = ((f * k) % 256 + 256) & 255;
    float s, c; sincosf((float)m * 0.0245436926061702596f, &s, &c);
    v = (n < 64) ? c : s;
    ph = pb1h; pl = pb1l;
  } else if (tb == 1) {
    int kb = (idx >> 9) & 15, mb = (idx >> 13) & 7;
    int mm = mb * 16 + lm;                   // row of [E;O]
    int k = kb * 32 + lg * 8 + e;            // (y, A|B half)
    int fy = (mm & 63) - 32;
    int y = k & 255;
    int m = ((fy * y) % 256 + 256) & 255;
    float s, c; sincosf((float)m * 0.0245436926061702596f, &s, &c);
    v = (mm < 64) ? ((k < 256) ? c : -s) : ((k < 256) ? s : c);
    ph = pa2h; pl = pa2l;
  } else if (tb == 2) {
    if (idx >= 32768) return;
    int nb = (idx >> 9) & 31, kb = (idx >> 14) & 1;
    int k = kb * 32 + lg * 8 + e;            // jx
    int n = nb * 16 + lm;                    // (x | 256+x)
    int f = k - 32;
    int xx = n & 255;
    int m = ((f * xx) % 256 + 256) & 255;
    float s, c; sincosf((float)m * 0.0245436926061702596f, &s, &c);
    v = (n < 256) ? c : s;
    ph = pb3h; pl = pb3l;
  } else {
    if (idx >= 32768) return;
    int kb = (idx >> 9) & 3, mb = (idx >> 11) & 15;
    int y = mb * 16 + lm;
    int k = kb * 32 + lg * 8 + e;            // (jy, P|M)
    int f = (k & 63) - 32;
    int m = ((f * y) % 256 + 256) & 255;
    float s, c; sincosf((float)m * 0.0245436926061702596f, &s, &c);
    v = (k < 64) ? (c + s) : (c - s);
    ph = pa4h; pl = pa4l;
  }
  u16 hb = f2bf(v);
  ph[idx] = hb;
  pl[idx] = f2bf(v - bf2f(hb));
}

// ---------------- kFwd: fused 2D forward partial DFT, one block per image ----------------
// P1: A|B[y 256][j 128] = Xsplit @ pb1 (3 mfma/prod) -> transposed swizzled LDS
// P2: [E;O][m 128][fx 64] = pa2[m][k 512] @ ABstack[k][fx] (2 mfma/prod)
__global__ __launch_bounds__(256, 2) void kFwd(const float* __restrict__ x,
    const u16* __restrict__ pb1h, const u16* __restrict__ pb1l,
    const u16* __restrict__ pa2h, const u16* __restrict__ pa2l,
    u16* __restrict__ E, u16* __restrict__ O) {
  __shared__ u16 ABT[32768];   // [j 128][y 256] bf16, byte ^ ((j&7)<<4), 64 KiB
  const int t = threadIdx.x;
  const int l = t & 63, w = t >> 6;
  const int lm = l & 15, lg = l >> 4;
  const int img = blockIdx.x;
  const float* xim = x + (long)img * 65536;

  // ---- phase 1: wave w owns y in [64w, 64w+64)
  f32x4 acc[4][8];
#pragma unroll
  for (int mt = 0; mt < 4; ++mt)
#pragma unroll
    for (int nb = 0; nb < 8; ++nb) acc[mt][nb] = (f32x4){0.f, 0.f, 0.f, 0.f};

  for (int kb = 0; kb < 8; ++kb) {
    short8 ah[4], al[4];
#pragma unroll
    for (int mt = 0; mt < 4; ++mt) {
      const float* px = xim + (long)(w * 64 + mt * 16 + lm) * 256 + kb * 32 + lg * 8;
      f32x4 v0 = *(const f32x4*)px;
      f32x4 v1 = *(const f32x4*)(px + 4);
#pragma unroll
      for (int i = 0; i < 8; ++i) {
        float vv = (i < 4) ? v0[i] : v1[i - 4];
        u16 hb = f2bf(vv);
        ah[mt][i] = (short)hb;
        al[mt][i] = (short)f2bf(vv - bf2f(hb));
      }
    }
#pragma unroll
    for (int nb = 0; nb < 8; ++nb) {
      long fo = (long)((kb * 8 + nb) * 64 + l) * 8;
      short8 bh = *(const short8*)(pb1h + fo);
      short8 bl = *(const short8*)(pb1l + fo);
#pragma unroll
      for (int mt = 0; mt < 4; ++mt) {
        acc[mt][nb] = mfma16(ah[mt], bh, acc[mt][nb]);
        acc[mt][nb] = mfma16(al[mt], bh, acc[mt][nb]);
        acc[mt][nb] = mfma16(ah[mt], bl, acc[mt][nb]);
      }
    }
  }
#pragma unroll
  for (int mt = 0; mt < 4; ++mt)
#pragma unroll
    for (int nb = 0; nb < 8; ++nb) {
      u32 j = (u32)(nb * 16 + lm);
      u32 y0 = (u32)(w * 64 + mt * 16 + lg * 4);
      u32 p0 = (u32)f2bf(acc[mt][nb][0]) | ((u32)f2bf(acc[mt][nb][1]) << 16);
      u32 p1 = (u32)f2bf(acc[mt][nb][2]) | ((u32)f2bf(acc[mt][nb][3]) << 16);
      u32 off = (j * 512 + y0 * 2) ^ ((j & 7) << 4);
      *(u32x2*)((char*)ABT + off) = (u32x2){p0, p1};
    }
  __syncthreads();

  // ---- phase 2: wave w owns rows m in [32w, 32w+32) of [E;O]
  f32x4 eo[2][4];
#pragma unroll
  for (int mt = 0; mt < 2; ++mt)
#pragma unroll
    for (int nb = 0; nb < 4; ++nb) eo[mt][nb] = (f32x4){0.f, 0.f, 0.f, 0.f};

  for (int kb = 0; kb < 16; ++kb) {
    short8 bfr[4];
    const int rbase = (kb < 8) ? 0 : 64;             // A-rows (cos cols) vs B-rows (sin cols)
    const u32 kbyte = (u32)(kb & 7) * 64 + (u32)lg * 16;
#pragma unroll
    for (int nb = 0; nb < 4; ++nb) {
      u32 row = (u32)(rbase + nb * 16 + lm);
      u32 off = (row * 512 + kbyte) ^ ((row & 7) << 4);
      bfr[nb] = *(const short8*)((const char*)ABT + off);
    }
#pragma unroll
    for (int mt = 0; mt < 2; ++mt) {
      int mb = w * 2 + mt;
      long fo = (long)((mb * 16 + kb) * 64 + l) * 8;
      short8 th = *(const short8*)(pa2h + fo);
      short8 tl = *(const short8*)(pa2l + fo);
#pragma unroll
      for (int nb = 0; nb < 4; ++nb) {
        eo[mt][nb] = mfma16(th, bfr[nb], eo[mt][nb]);
        eo[mt][nb] = mfma16(tl, bfr[nb], eo[mt][nb]);
      }
    }
  }
  u16* dst = (w < 2) ? E : O;
  const long ebase = (long)img * 4096;
  const int fyb = (w & 1) * 32;
#pragma unroll
  for (int mt = 0; mt < 2; ++mt)
#pragma unroll
    for (int nb = 0; nb < 4; ++nb) {
      int fy0 = fyb + mt * 16 + lg * 4;
      int fx = nb * 16 + lm;
#pragma unroll
      for (int r = 0; r < 4; ++r)
        dst[ebase + (long)(fy0 + r) * 64 + fx] = f2bf(eo[mt][nb][r]);
    }
}

// ---------------- u16 transpose: in[M][N] -> out[N][M] (z selects pair) ----------------
__global__ __launch_bounds__(256) void kt_u16(const u16* __restrict__ in0, u16* __restrict__ out0,
                                              const u16* __restrict__ in1, u16* __restrict__ out1,
                                              int M, int N) {
  __shared__ u16 tile[32][36];
  const u16* in = blockIdx.z ? in1 : in0;
  u16* out = blockIdx.z ? out1 : out0;
  int tx = threadIdx.x & 31, ty = threadIdx.x >> 5;
  long c0 = (long)blockIdx.x * 32, r0 = (long)blockIdx.y * 32;
#pragma unroll
  for (int i = 0; i < 4; ++i) {
    int r = ty + i * 8;
    tile[r][tx] = in[(r0 + r) * N + c0 + tx];
  }
  __syncthreads();
#pragma unroll
  for (int i = 0; i < 4; ++i) {
    int r = ty + i * 8;
    out[(c0 + r) * M + r0 + tx] = tile[tx][r];
  }
}

// ---------------- kt_f32: fp32 transpose w[e 4096][mode 4096] -> w2[mode][e] ----------------
__global__ __launch_bounds__(256) void kt_f32(const float* __restrict__ in, float* __restrict__ out) {
  __shared__ float tile[32][33];
  int tx = threadIdx.x & 31, ty = threadIdx.x >> 5;
  long c0 = (long)blockIdx.x * 32, r0 = (long)blockIdx.y * 32;
#pragma unroll
  for (int i = 0; i < 4; ++i) {
    int r = ty + i * 8;
    tile[r][tx] = in[(r0 + r) * 4096 + c0 + tx];
  }
  __syncthreads();
#pragma unroll
  for (int i = 0; i < 4; ++i) {
    int r = ty + i * 8;
    out[(c0 + r) * 4096 + r0 + tx] = tile[tx][r];
  }
}

// ---------------- k5: per-mode channel mix, G[b][o] = sum_i E*w + O*kr ----------------
// R4: reads mode-major w2[mode][e] -- two contiguous 16KB rows per block, float4.
__global__ __launch_bounds__(256) void k5_mix(const u16* __restrict__ Et, const u16* __restrict__ Ot,
    const float* __restrict__ w2, u16* __restrict__ Gt) {
  __shared__ float Ews[1024], Ows[1024];
  __shared__ float Ws[4096], Ks[4096];
  const int t = threadIdx.x;
  const int mode = blockIdx.x;
  const int jy = mode >> 6, jx = mode & 63;
  const int fm = (((64 - jy) & 63) << 6) | ((64 - jx) & 63);
  ushort4 ve = ((const ushort4*)Et)[(long)mode * 256 + t];
  ushort4 vo = ((const ushort4*)Ot)[(long)mode * 256 + t];
  Ews[t * 4 + 0] = bf2f(ve.x); Ews[t * 4 + 1] = bf2f(ve.y);
  Ews[t * 4 + 2] = bf2f(ve.z); Ews[t * 4 + 3] = bf2f(ve.w);
  Ows[t * 4 + 0] = bf2f(vo.x); Ows[t * 4 + 1] = bf2f(vo.y);
  Ows[t * 4 + 2] = bf2f(vo.z); Ows[t * 4 + 3] = bf2f(vo.w);
  const float4* wr = (const float4*)(w2 + (long)mode * 4096);
  const float4* kr = (const float4*)(w2 + (long)fm * 4096);
#pragma unroll
  for (int it = 0; it < 4; ++it) {
    ((float4*)Ws)[it * 256 + t] = wr[it * 256 + t];
    ((float4*)Ks)[it * 256 + t] = kr[it * 256 + t];
  }
  __syncthreads();
  const int o = t & 63, bg = t >> 6;
  float acc[4] = {0.f, 0.f, 0.f, 0.f};
  for (int i = 0; i < 64; ++i) {
    float wv = Ws[i * 64 + o];
    float kv = Ks[i * 64 + o];
#pragma unroll
    for (int j = 0; j < 4; ++j) {
      int b = bg * 4 + j;
      acc[j] = fmaf(Ews[b * 64 + i], wv, acc[j]);
      acc[j] = fmaf(Ows[b * 64 + i], kv, acc[j]);
    }
  }
#pragma unroll
  for (int j = 0; j < 4; ++j)
    Gt[(long)mode * 1024 + (bg * 4 + j) * 64 + o] = f2bf(acc[j]);
}

// ---------------- kInv: fused 2D inverse, one block per output image (bo) ----------------
// PA: HH[k' 128][x] = G @ pb3 (2 mfma/prod) -> transposed swizzled LDS (half of x at a time)
// PB: out[y][x] = pa4[y][k 128] @ HHT, fused *(1/65536)+bias, relu
// R5 epilogue: per-wave LDS bounce -> float4 nontemporal full-line stores.
__global__ __launch_bounds__(256, 2) void kInv(const u16* __restrict__ G,
    const u16* __restrict__ pb3h, const u16* __restrict__ pb3l,
    const u16* __restrict__ pa4h, const u16* __restrict__ pa4l,
    const float* __restrict__ bias, float* __restrict__ out) {
  __shared__ u16 Gls[4096];        // [jy 64][jx 64], byte ^ ((jy&7)<<4), 8 KiB
  __shared__ u16 HHT[16384];       // [xl 128][k' 128], byte ^ ((xl&7)<<4), 32 KiB
  __shared__ float Ost[4][16][68]; // per-wave out staging, pad 68 (16B-aligned rows, bank-rotated), 17 KiB
  const int t = threadIdx.x;
  const int l = t & 63, w = t >> 6;
  const int lm = l & 15, lg = l >> 4;
  const int bo = blockIdx.x;

#pragma unroll
  for (int it = 0; it < 2; ++it) {
    int tt = t + it * 256;
    uint4 v = ((const uint4*)(G + (long)bo * 4096))[tt];
    u32 jy = (u32)(tt >> 3);
    u32 off = (jy * 128 + (u32)(tt & 7) * 16) ^ ((jy & 7) << 4);
    *(uint4*)((char*)Gls + off) = v;
  }
  __syncthreads();

  const float bv = bias[bo & 63];
  const int comp = w >> 1;        // 0: H1 (cos), 1: H2 (sin)
  const int xw = (w & 1) * 64;    // x offset inside the 128-wide half

  for (int h = 0; h < 2; ++h) {
    if (h) __syncthreads();       // phase-B reads of previous half done
    // ---- phase A: this wave computes comp-part, xl in [xw, xw+64)
    f32x4 ha[4][4];
#pragma unroll
    for (int mt = 0; mt < 4; ++mt)
#pragma unroll
      for (int nb = 0; nb < 4; ++nb) ha[mt][nb] = (f32x4){0.f, 0.f, 0.f, 0.f};

    const int nbase = comp * 16 + h * 8 + (w & 1) * 4;   // (comp*256 + h*128 + xw)/16
#pragma unroll
    for (int kb = 0; kb < 2; ++kb) {
      short8 af[4];
#pragma unroll
      for (int mt = 0; mt < 4; ++mt) {
        u32 row = (u32)(mt * 16 + lm);
        u32 off = (row * 128 + (u32)kb * 64 + (u32)lg * 16) ^ ((row & 7) << 4);
        af[mt] = *(const short8*)((const char*)Gls + off);
      }
#pragma unroll
      for (int nb = 0; nb < 4; ++nb) {
        long fo = (long)((kb * 32 + nbase + nb) * 64 + l) * 8;
        short8 bh = *(const short8*)(pb3h + fo);
        short8 bl = *(const short8*)(pb3l + fo);
#pragma unroll
        for (int mt = 0; mt < 4; ++mt) {
          ha[mt][nb] = mfma16(af[mt], bh, ha[mt][nb]);
          ha[mt][nb] = mfma16(af[mt], bl, ha[mt][nb]);
        }
      }
    }
#pragma unroll
    for (int mt = 0; mt < 4; ++mt)
#pragma unroll
      for (int nb = 0; nb < 4; ++nb) {
        u32 xl = (u32)(xw + nb * 16 + lm);
        u32 kp = (u32)(comp * 64 + mt * 16 + lg * 4);
        u32 p0 = (u32)f2bf(ha[mt][nb][0]) | ((u32)f2bf(ha[mt][nb][1]) << 16);
        u32 p1 = (u32)f2bf(ha[mt][nb][2]) | ((u32)f2bf(ha[mt][nb][3]) << 16);
        u32 off = (xl * 256 + kp * 2) ^ ((xl & 7) << 4);
        *(u32x2*)((char*)HHT + off) = (u32x2){p0, p1};
      }
    __syncthreads();

    // ---- phase B: wave w owns y in [64w, 64w+64); x = this half
#pragma unroll
    for (int q = 0; q < 2; ++q) {
      f32x4 oa[4][4];
#pragma unroll
      for (int mt = 0; mt < 4; ++mt)
#pragma unroll
        for (int nb = 0; nb < 4; ++nb) oa[mt][nb] = (f32x4){0.f, 0.f, 0.f, 0.f};
#pragma unroll
      for (int kb = 0; kb < 4; ++kb) {
        short8 bf_[4];
#pragma unroll
        for (int nb = 0; nb < 4; ++nb) {
          u32 xl = (u32)(q * 64 + nb * 16 + lm);
          u32 off = (xl * 256 + (u32)kb * 64 + (u32)lg * 16) ^ ((xl & 7) << 4);
          bf_[nb] = *(const short8*)((const char*)HHT + off);
        }
#pragma unroll
        for (int mt = 0; mt < 4; ++mt) {
          int mb = w * 4 + mt;
          long fo = (long)((mb * 4 + kb) * 64 + l) * 8;
          short8 th = *(const short8*)(pa4h + fo);
          short8 tl = *(const short8*)(pa4l + fo);
#pragma unroll
          for (int nb = 0; nb < 4; ++nb) {
            oa[mt][nb] = mfma16(th, bf_[nb], oa[mt][nb]);
            oa[mt][nb] = mfma16(tl, bf_[nb], oa[mt][nb]);
          }
        }
      }
      // R5 epilogue: stage per-wave 16x64 f32 subtile in LDS (wave-local, no
      // barrier), then 16B/lane nontemporal stores: each 16-lane group covers
      // 256B contiguous = 2 full 128B lines -> no RFO fetch, single write.
      const float inv = 1.0f / 65536.0f;
      const int xbase = h * 128 + q * 64;
#pragma unroll
      for (int mt = 0; mt < 4; ++mt) {
#pragma unroll
        for (int nb = 0; nb < 4; ++nb)
#pragma unroll
          for (int r = 0; r < 4; ++r) {
            float v = fmaf(oa[mt][nb][r], inv, bv);
            Ost[w][lg * 4 + r][nb * 16 + lm] = fmaxf(v, 0.f);
          }
#pragma unroll
        for (int it = 0; it < 4; ++it) {
          f32x4 vv = *(const f32x4*)&Ost[w][it * 4 + lg][lm * 4];
          float* dst = &out[(long)bo * 65536 + (long)(w * 64 + mt * 16 + it * 4 + lg) * 256 + xbase + lm * 4];
          __builtin_nontemporal_store(vv, (f32x4*)dst);
        }
      }
    }
  }
}

extern "C" void kernel_launch(void* const* d_in, const int* in_sizes, int n_in,
                              void* d_out, int out_size, void* d_ws, size_t ws_size,
                              hipStream_t stream) {
  const float* x    = (const float*)d_in[0];   // [16][64][256][256] fp32
  const float* w    = (const float*)d_in[1];   // [64][64][64][64]   fp32
  const float* bias = (const float*)d_in[2];   // [64]               fp32
  float* out = (float*)d_out;                  // [16][64][256][256] fp32
  char* ws = (char*)d_ws;

  // persistent tables (needed by kInv at the end):
  u16* pb3h = (u16*)(ws + 0);
  u16* pb3l = (u16*)(ws + 65536);
  u16* pa4h = (u16*)(ws + 131072);
  u16* pa4l = (u16*)(ws + 196608);
  // E/O [img][mode] bf16, 8 MiB each:
  u16* E    = (u16*)(ws + 262144);
  u16* O    = (u16*)(ws + 8650752);
  u16* Et   = (u16*)(ws + 17039360);
  u16* Ot   = (u16*)(ws + 25427968);
  // transient fwd tables live in the head of the (not-yet-written) Et region;
  // kt_u16 #1 clobbers them only after kFwd has finished reading them:
  u16* pb1h = (u16*)(ws + 17039360);
  u16* pb1l = (u16*)(ws + 17104896);
  u16* pa2h = (u16*)(ws + 17170432);
  u16* pa2l = (u16*)(ws + 17301504);
  u16* Gt   = (u16*)(ws + 262144);     // over dead E
  u16* G    = (u16*)(ws + 8650752);    // over dead O
  // peak workspace: 33,816,576 bytes (unchanged)

  // w2[mode][e] fp32 (64 MB) lives in the HEAD OF d_out -- d_out is 256 MB and
  // is only written by kInv (last kernel), so the scratch lifetime is safe.
  float* w2 = (float*)d_out;

  k0_pack<<<dim3(256, 4), 256, 0, stream>>>(pb1h, pb1l, pa2h, pa2l, pb3h, pb3l, pa4h, pa4l);
  kt_f32 <<<dim3(128, 128), 256, 0, stream>>>(w, w2);
  kFwd   <<<1024, 256, 0, stream>>>(x, pb1h, pb1l, pa2h, pa2l, E, O);
  kt_u16 <<<dim3(128, 32, 2), 256, 0, stream>>>(E, Et, O, Ot, 1024, 4096);
  k5_mix <<<4096, 256, 0, stream>>>(Et, Ot, w2, Gt);
  kt_u16 <<<dim3(32, 128, 1), 256, 0, stream>>>(Gt, G, Gt, G, 4096, 1024);
  kInv   <<<1024, 256, 0, stream>>>(G, pb3h, pb3l, pa4h, pa4l, bias, out);
}